// Round 5
// baseline (181.660 us; speedup 1.0000x reference)
//
#include <hip/hip_runtime.h>
#include <stdint.h>

typedef float          f32x4  __attribute__((ext_vector_type(4)));
typedef __bf16         bf16x8 __attribute__((ext_vector_type(8)));
typedef unsigned short u16x4  __attribute__((ext_vector_type(4)));
typedef unsigned short u16x8  __attribute__((ext_vector_type(8)));

__device__ __forceinline__ float bf2f(unsigned short u) {
    union { uint32_t i; float f; } v; v.i = ((uint32_t)u) << 16; return v.f;
}
__device__ __forceinline__ unsigned short bfc(float f) {
    return __builtin_bit_cast(unsigned short, (__bf16)f);
}
__device__ __forceinline__ f32x4 mfma16(bf16x8 a, bf16x8 b, f32x4 c) {
    return __builtin_amdgcn_mfma_f32_16x16x32_bf16(a, b, c, 0, 0, 0);
}
// async global->LDS, 16B per lane; LDS dest = wave-uniform base + lane*16
__device__ __forceinline__ void async16(const unsigned short* g, unsigned short* l) {
    __builtin_amdgcn_global_load_lds(
        (const __attribute__((address_space(1))) void*)g,
        (__attribute__((address_space(3))) void*)l, 16, 0, 0);
}

#define QSC 0.18033688f   /* 0.125 * log2(e): S produced in exp2 domain */

// ---------------------------------------------------------------------------
// Kernel 1: QKV GEMM.  C[o][n] = sum_c Wqkv[o][c] * X[b][c][n],  o in [0,768)
// f32 inputs -> bf16 LDS staging.  Q written pre-scaled by 0.125*log2e.
// Q,K layout [bh][n][d]; V layout [bh][d][m].
// ---------------------------------------------------------------------------
__global__ __launch_bounds__(256) void qkv_gemm(
    const float* __restrict__ x, const float* __restrict__ wqkv,
    unsigned short* __restrict__ Qb, unsigned short* __restrict__ Kb,
    unsigned short* __restrict__ Vb) {
    const int mt = blockIdx.x;          // 0..5
    const int nt = blockIdx.y;          // 0..31
    const int b  = blockIdx.z;          // 0..3
    const int o0 = mt * 128, n0 = nt * 128;
    __shared__ __align__(16) unsigned short Wt[128 * 72];   // [o][c] pad 72
    __shared__ __align__(16) unsigned short Xt[128 * 72];   // [n][c] pad 72
    const int t = threadIdx.x;
    const int lane = t & 63, w = t >> 6;
    const int wr = w >> 1, wc = w & 1;
    const int l15 = lane & 15, g = lane >> 4;

    f32x4 acc[4][4];
    const f32x4 zero = {0.f, 0.f, 0.f, 0.f};
    for (int i = 0; i < 4; i++) for (int j = 0; j < 4; j++) acc[i][j] = zero;

    for (int k0 = 0; k0 < 256; k0 += 64) {
        {
            const int row = t >> 3, col = (t & 7) * 8;
            #pragma unroll
            for (int r = 0; r < 4; r++) {
                const float* p = wqkv + (size_t)(o0 + row + r * 32) * 256 + k0 + col;
                f32x4 v0 = *(const f32x4*)p;
                f32x4 v1 = *(const f32x4*)(p + 4);
                u16x8 o8 = { bfc(v0[0]), bfc(v0[1]), bfc(v0[2]), bfc(v0[3]),
                             bfc(v1[0]), bfc(v1[1]), bfc(v1[2]), bfc(v1[3]) };
                *(u16x8*)(&Wt[(row + r * 32) * 72 + col]) = o8;
            }
        }
        {
            const int cl = t >> 4, nl = (t & 15) * 8;
            #pragma unroll
            for (int r = 0; r < 4; r++) {
                const int c = k0 + cl + r * 16;
                const float* p = x + (size_t)(b * 512 + c) * 4096 + n0 + nl;
                f32x4 v0 = *(const f32x4*)p;
                f32x4 v1 = *(const f32x4*)(p + 4);
                #pragma unroll
                for (int j = 0; j < 4; j++) Xt[(nl + j) * 72 + cl + r * 16] = bfc(v0[j]);
                #pragma unroll
                for (int j = 0; j < 4; j++) Xt[(nl + 4 + j) * 72 + cl + r * 16] = bfc(v1[j]);
            }
        }
        __syncthreads();
        #pragma unroll
        for (int kk = 0; kk < 2; kk++) {
            bf16x8 af[4], bfr[4];
            #pragma unroll
            for (int i = 0; i < 4; i++)
                af[i] = *(const bf16x8*)(&Wt[(wr * 64 + i * 16 + l15) * 72 + kk * 32 + g * 8]);
            #pragma unroll
            for (int j = 0; j < 4; j++)
                bfr[j] = *(const bf16x8*)(&Xt[(wc * 64 + j * 16 + l15) * 72 + kk * 32 + g * 8]);
            #pragma unroll
            for (int i = 0; i < 4; i++)
                #pragma unroll
                for (int j = 0; j < 4; j++)
                    acc[i][j] = mfma16(af[i], bfr[j], acc[i][j]);
        }
        __syncthreads();
    }

    #pragma unroll
    for (int i = 0; i < 4; i++) {
        const int o = o0 + wr * 64 + i * 16 + g * 4;
        #pragma unroll
        for (int j = 0; j < 4; j++) {
            const int n = n0 + wc * 64 + j * 16 + l15;
            f32x4 a = acc[i][j];
            if (o < 256) {
                u16x4 pv = { bfc(a[0] * QSC), bfc(a[1] * QSC), bfc(a[2] * QSC), bfc(a[3] * QSC) };
                const int h = o >> 6, d = o & 63;
                *(u16x4*)(&Qb[(((size_t)(b * 4 + h)) * 4096 + n) * 64 + d]) = pv;
            } else if (o < 512) {
                u16x4 pv = { bfc(a[0]), bfc(a[1]), bfc(a[2]), bfc(a[3]) };
                const int oo = o - 256; const int h = oo >> 6, d = oo & 63;
                *(u16x4*)(&Kb[(((size_t)(b * 4 + h)) * 4096 + n) * 64 + d]) = pv;
            } else {
                const int oo = o - 512; const int h = oo >> 6, d = oo & 63;
                const size_t base = (((size_t)(b * 4 + h)) * 64 + d) * 4096 + n;
                Vb[base] = bfc(a[0]); Vb[base + 4096] = bfc(a[1]);
                Vb[base + 8192] = bfc(a[2]); Vb[base + 12288] = bfc(a[3]);
            }
        }
    }
}

// ---------------------------------------------------------------------------
// Kernel 2: flash attention.  4 waves x 32 q-rows (QBLK=128), KVBLK=64.
// K,V double-buffered linear [64][64] LDS via global_load_lds, XOR swizzle
// (elem ^= (row&7)<<3) on reads, pre-swizzled global sources.  Unroll-2 so
// the LDS buffer index is compile-time (ds_read offsets become immediates).
// S in exp2 domain.  Defer-max (THR=8), per-lane vectored l accumulation.
// ---------------------------------------------------------------------------
__global__ __launch_bounds__(256, 2) void flash_attn(
    const unsigned short* __restrict__ Qb, const unsigned short* __restrict__ Kb,
    const unsigned short* __restrict__ Vb, unsigned short* __restrict__ att) {
    __shared__ __align__(16) unsigned short Kt[2][64 * 64];   // 16 KB
    __shared__ __align__(16) unsigned short Vt[2][64 * 64];   // 16 KB
    __shared__ __align__(16) unsigned short Pt[4][32 * 64];   // 16 KB

    // XCD-aware swizzle: 512 blocks, 8 XCDs, 64 consecutive blocks per XCD
    const int flat = blockIdx.y * 32 + blockIdx.x;
    const int swz = (flat & 7) * 64 + (flat >> 3);
    const int bh = swz >> 5;            // 0..15
    const int nb = swz & 31;            // 0..31  (q-tile of 128)

    const int t = threadIdx.x, lane = t & 63, w = t >> 6;    // w = 0..3
    const int l15 = lane & 15, g = lane >> 4;
    const int xo = (l15 & 7) << 3;              // element-space XOR for reads
    const int c0 = (g * 8) ^ xo, c1 = c0 ^ 32;

    // staging source addresses (pre-swizzled, within each 128B row)
    const int rb = lane >> 3;                                  // 0..7
    const int cbe = ((lane & 7) ^ rb) << 3;                    // element col offset
    const unsigned short* kgp = Kb + ((size_t)bh * 4096 + w * 8 + rb) * 64 + cbe;
    const unsigned short* vgp = Vb + ((size_t)(bh * 64 + w * 8 + rb)) * 4096 + cbe;

    auto stage = [&](int buf) {           // loads NEXT kv-tile, advances ptrs
        async16(kgp,          &Kt[buf][w * 512]);
        async16(kgp + 2048,   &Kt[buf][w * 512 + 2048]);
        async16(vgp,          &Vt[buf][w * 512]);
        async16(vgp + 131072, &Vt[buf][w * 512 + 2048]);
        kgp += 4096; vgp += 64;
    };

    // Q fragments (scaled into exp2 domain at QKV epilogue)
    bf16x8 qf[2][2];
    #pragma unroll
    for (int ntl = 0; ntl < 2; ++ntl) {
        const int nq = nb * 128 + w * 32 + ntl * 16 + l15;
        const unsigned short* qp = Qb + ((size_t)bh * 4096 + nq) * 64;
        qf[ntl][0] = *(const bf16x8*)(qp + g * 8);
        qf[ntl][1] = *(const bf16x8*)(qp + 32 + g * 8);
    }

    f32x4 of[4][2];
    f32x4 lr[2];
    const f32x4 zero = {0.f, 0.f, 0.f, 0.f};
    #pragma unroll
    for (int dt = 0; dt < 4; ++dt) { of[dt][0] = zero; of[dt][1] = zero; }
    lr[0] = zero; lr[1] = zero;
    float mr[2] = {-1e30f, -1e30f};

    unsigned short* Pw = &Pt[w][0];

    stage(0);
    __syncthreads();

    for (int itp = 0; itp < 32; ++itp) {
        #pragma unroll
        for (int cur = 0; cur < 2; ++cur) {          // cur is compile-time
            const int iter = itp * 2 + cur;
            if (iter < 63) stage(cur ^ 1);

            // S^T[m][n] (exp2 domain): m = mt*16+g*4+r, n = ntl*16+l15
            f32x4 st[4][2];
            __builtin_amdgcn_s_setprio(1);
            #pragma unroll
            for (int mt = 0; mt < 4; ++mt) {
                const int kro = (mt * 16 + l15) * 64;
                bf16x8 ka0 = *(const bf16x8*)(&Kt[cur][kro + c0]);
                bf16x8 ka1 = *(const bf16x8*)(&Kt[cur][kro + c1]);
                st[mt][0] = mfma16(ka1, qf[0][1], mfma16(ka0, qf[0][0], zero));
                st[mt][1] = mfma16(ka1, qf[1][1], mfma16(ka0, qf[1][0], zero));
            }
            __builtin_amdgcn_s_setprio(0);

            #pragma unroll
            for (int ntl = 0; ntl < 2; ++ntl) {
                float a0 = fmaxf(fmaxf(st[0][ntl][0], st[0][ntl][1]), fmaxf(st[0][ntl][2], st[0][ntl][3]));
                float a1 = fmaxf(fmaxf(st[1][ntl][0], st[1][ntl][1]), fmaxf(st[1][ntl][2], st[1][ntl][3]));
                float a2 = fmaxf(fmaxf(st[2][ntl][0], st[2][ntl][1]), fmaxf(st[2][ntl][2], st[2][ntl][3]));
                float a3 = fmaxf(fmaxf(st[3][ntl][0], st[3][ntl][1]), fmaxf(st[3][ntl][2], st[3][ntl][3]));
                float tm = fmaxf(fmaxf(a0, a1), fmaxf(a2, a3));
                tm = fmaxf(tm, __shfl_xor(tm, 16, 64));
                tm = fmaxf(tm, __shfl_xor(tm, 32, 64));

                if (!__all(tm <= mr[ntl] + 8.f)) {
                    const float mnew = fmaxf(mr[ntl], tm);
                    const float al = __builtin_amdgcn_exp2f(mr[ntl] - mnew);
                    #pragma unroll
                    for (int dt = 0; dt < 4; ++dt)
                        #pragma unroll
                        for (int r = 0; r < 4; ++r) of[dt][ntl][r] *= al;
                    #pragma unroll
                    for (int r = 0; r < 4; ++r) lr[ntl][r] *= al;
                    mr[ntl] = mnew;
                }

                #pragma unroll
                for (int mt = 0; mt < 4; ++mt) {
                    f32x4 p;
                    #pragma unroll
                    for (int r = 0; r < 4; ++r) {
                        p[r] = __builtin_amdgcn_exp2f(st[mt][ntl][r] - mr[ntl]);
                        lr[ntl][r] += p[r];
                    }
                    u16x4 pv = { bfc(p[0]), bfc(p[1]), bfc(p[2]), bfc(p[3]) };
                    *(u16x4*)(&Pw[(ntl * 16 + l15) * 64 + ((mt * 16 + g * 4) ^ xo)]) = pv;
                }
            }

            // O^T[d][n] += V[d][m] . P^T[m][n]
            bf16x8 pb00 = *(const bf16x8*)(&Pw[l15 * 64 + c0]);
            bf16x8 pb01 = *(const bf16x8*)(&Pw[l15 * 64 + c1]);
            bf16x8 pb10 = *(const bf16x8*)(&Pw[(16 + l15) * 64 + c0]);
            bf16x8 pb11 = *(const bf16x8*)(&Pw[(16 + l15) * 64 + c1]);
            __builtin_amdgcn_s_setprio(1);
            #pragma unroll
            for (int dt = 0; dt < 4; ++dt) {
                const int vro = (dt * 16 + l15) * 64;
                bf16x8 va0 = *(const bf16x8*)(&Vt[cur][vro + c0]);
                bf16x8 va1 = *(const bf16x8*)(&Vt[cur][vro + c1]);
                of[dt][0] = mfma16(va1, pb01, mfma16(va0, pb00, of[dt][0]));
                of[dt][1] = mfma16(va1, pb11, mfma16(va0, pb10, of[dt][1]));
            }
            __builtin_amdgcn_s_setprio(0);
            __syncthreads();        // drains prefetch + guards buffer swap
        }
    }

    // epilogue: reduce per-lane l partials, att[b][n][h*64+d] = O / l
    const int b = bh >> 2, h = bh & 3;
    #pragma unroll
    for (int ntl = 0; ntl < 2; ++ntl) {
        float l = lr[ntl][0] + lr[ntl][1] + lr[ntl][2] + lr[ntl][3];
        l += __shfl_xor(l, 16, 64);
        l += __shfl_xor(l, 32, 64);
        const float inv = 1.f / l;
        const int nq = nb * 128 + w * 32 + ntl * 16 + l15;
        #pragma unroll
        for (int dt = 0; dt < 4; ++dt) {
            u16x4 pv = { bfc(of[dt][ntl][0] * inv), bfc(of[dt][ntl][1] * inv),
                         bfc(of[dt][ntl][2] * inv), bfc(of[dt][ntl][3] * inv) };
            *(u16x4*)(&att[(((size_t)b) * 4096 + nq) * 256 + h * 64 + dt * 16 + g * 4]) = pv;
        }
    }
}

// ---------------------------------------------------------------------------
// Kernel 3: proj GEMM.  projbf[b][o][n] (bf16) = sum_c Wp[o][c] * att[b][n][c]
// Epilogue also emits per-(block,wave) BN partial sums (deterministic).
// ---------------------------------------------------------------------------
__global__ __launch_bounds__(256) void proj_gemm(
    const unsigned short* __restrict__ att, const float* __restrict__ wproj,
    unsigned short* __restrict__ projbf, float* __restrict__ psum) {
    const int mt = blockIdx.x;          // 0..1
    const int nt = blockIdx.y;          // 0..31
    const int b  = blockIdx.z;          // 0..3
    const int o0 = mt * 128, n0 = nt * 128;
    __shared__ __align__(16) unsigned short Wt[128 * 72];
    __shared__ __align__(16) unsigned short Bt[128 * 72];
    const int t = threadIdx.x;
    const int lane = t & 63, w = t >> 6;
    const int wr = w >> 1, wc = w & 1;
    const int l15 = lane & 15, g = lane >> 4;

    f32x4 acc[4][4];
    const f32x4 zero = {0.f, 0.f, 0.f, 0.f};
    for (int i = 0; i < 4; i++) for (int j = 0; j < 4; j++) acc[i][j] = zero;

    for (int k0 = 0; k0 < 256; k0 += 64) {
        const int row = t >> 3, col = (t & 7) * 8;
        #pragma unroll
        for (int r = 0; r < 4; r++) {
            const float* p = wproj + (size_t)(o0 + row + r * 32) * 256 + k0 + col;
            f32x4 v0 = *(const f32x4*)p;
            f32x4 v1 = *(const f32x4*)(p + 4);
            u16x8 o8 = { bfc(v0[0]), bfc(v0[1]), bfc(v0[2]), bfc(v0[3]),
                         bfc(v1[0]), bfc(v1[1]), bfc(v1[2]), bfc(v1[3]) };
            *(u16x8*)(&Wt[(row + r * 32) * 72 + col]) = o8;
            u16x8 a = *(const u16x8*)(att + (((size_t)b) * 4096 + n0 + row + r * 32) * 256 + k0 + col);
            *(u16x8*)(&Bt[(row + r * 32) * 72 + col]) = a;
        }
        __syncthreads();
        #pragma unroll
        for (int kk = 0; kk < 2; kk++) {
            bf16x8 af[4], bfr[4];
            #pragma unroll
            for (int i = 0; i < 4; i++)
                af[i] = *(const bf16x8*)(&Wt[(wr * 64 + i * 16 + l15) * 72 + kk * 32 + g * 8]);
            #pragma unroll
            for (int j = 0; j < 4; j++)
                bfr[j] = *(const bf16x8*)(&Bt[(wc * 64 + j * 16 + l15) * 72 + kk * 32 + g * 8]);
            #pragma unroll
            for (int i = 0; i < 4; i++)
                #pragma unroll
                for (int j = 0; j < 4; j++)
                    acc[i][j] = mfma16(af[i], bfr[j], acc[i][j]);
        }
        __syncthreads();
    }

    #pragma unroll
    for (int i = 0; i < 4; i++) {
        const int o = o0 + wr * 64 + i * 16 + g * 4;
        #pragma unroll
        for (int j = 0; j < 4; j++) {
            const int n = n0 + wc * 64 + j * 16 + l15;
            f32x4 a = acc[i][j];
            #pragma unroll
            for (int r = 0; r < 4; r++)
                projbf[((size_t)(b * 256 + o + r)) * 4096 + n] = bfc(a[r]);
        }
        // BN partials over this wave's 64 n-columns (f32, pre-rounding)
        f32x4 s = acc[i][0], q;
        #pragma unroll
        for (int r = 0; r < 4; ++r) q[r] = acc[i][0][r] * acc[i][0][r];
        #pragma unroll
        for (int j = 1; j < 4; ++j)
            #pragma unroll
            for (int r = 0; r < 4; ++r) {
                s[r] += acc[i][j][r];
                q[r] = fmaf(acc[i][j][r], acc[i][j][r], q[r]);
            }
        #pragma unroll
        for (int m = 1; m < 16; m <<= 1) {
            #pragma unroll
            for (int r = 0; r < 4; ++r) {
                s[r] += __shfl_xor(s[r], m, 64);
                q[r] += __shfl_xor(q[r], m, 64);
            }
        }
        if (l15 == 0) {
            const int slot = (b * 32 + nt) * 2 + wc;
            *(f32x4*)(&psum[slot * 256 + o]) = s;
            *(f32x4*)(&psum[65536 + slot * 256 + o]) = q;
        }
    }
}

// ---------------------------------------------------------------------------
// Kernel 4: BN finalize.  256 threads; channel o reduces 256 slot partials.
// ---------------------------------------------------------------------------
__global__ __launch_bounds__(256) void bn_finalize(const float* __restrict__ psum,
                                                   float* __restrict__ stats) {
    const int o = threadIdx.x;
    float s = 0.f, q = 0.f;
    for (int sl = 0; sl < 256; ++sl) {
        s += psum[sl * 256 + o];
        q += psum[65536 + sl * 256 + o];
    }
    const float mean = s * (1.f / 16384.f);
    const float var = q * (1.f / 16384.f) - mean * mean;
    stats[o] = mean;
    stats[256 + o] = rsqrtf(var + 1e-5f);
}

// ---------------------------------------------------------------------------
// Kernel 5: BN apply + gamma/beta + concat skip.  proj bf16 in, f32 out.
// ---------------------------------------------------------------------------
__global__ __launch_bounds__(256) void bn_apply(
    const unsigned short* __restrict__ projbf, const float* __restrict__ stats,
    const float* __restrict__ gamma, const float* __restrict__ beta,
    const float* __restrict__ x, float* __restrict__ out) {
    const size_t idx8 = ((size_t)blockIdx.x * 256 + threadIdx.x) * 8;
    const int n  = (int)(idx8 & 4095);
    const int ch = (int)((idx8 >> 12) & 511);
    const int b  = (int)(idx8 >> 21);
    if (ch < 256) {
        const float mean = stats[ch], rstd = stats[256 + ch];
        const float sc = gamma[ch] * rstd;
        const float sh = beta[ch] - mean * sc;
        u16x8 pv = *(const u16x8*)(projbf + (((size_t)(b * 256 + ch)) << 12) + n);
        f32x4 o0, o1;
        #pragma unroll
        for (int j = 0; j < 4; j++) { o0[j] = bf2f(pv[j]) * sc + sh; o1[j] = bf2f(pv[4 + j]) * sc + sh; }
        *(f32x4*)(out + idx8) = o0;
        *(f32x4*)(out + idx8 + 4) = o1;
    } else {
        *(f32x4*)(out + idx8)     = *(const f32x4*)(x + idx8);
        *(f32x4*)(out + idx8 + 4) = *(const f32x4*)(x + idx8 + 4);
    }
}

// ---------------------------------------------------------------------------
extern "C" void kernel_launch(void* const* d_in, const int* in_sizes, int n_in,
                              void* d_out, int out_size, void* d_ws, size_t ws_size,
                              hipStream_t stream) {
    const float* x     = (const float*)d_in[0];
    const float* wqkv  = (const float*)d_in[1];
    const float* wproj = (const float*)d_in[2];
    const float* gamma = (const float*)d_in[3];
    const float* beta  = (const float*)d_in[4];
    float* out = (float*)d_out;

    char* ws = (char*)d_ws;
    unsigned short* Qb     = (unsigned short*)(ws);                 // 8 MB
    unsigned short* Kb     = (unsigned short*)(ws + (8u  << 20));   // 8 MB
    unsigned short* Vb     = (unsigned short*)(ws + (16u << 20));   // 8 MB
    unsigned short* att    = (unsigned short*)(ws + (24u << 20));   // 8 MB
    unsigned short* projbf = (unsigned short*)(ws + (32u << 20));   // 8.4 MB
    float*          psum   = (float*)(ws + (41u << 20));            // 512 KB
    float*          stats  = (float*)(ws + (42u << 20));            // 2 KB

    qkv_gemm   <<<dim3(6, 32, 4), 256, 0, stream>>>(x, wqkv, Qb, Kb, Vb);
    flash_attn <<<dim3(32, 16),   256, 0, stream>>>(Qb, Kb, Vb, att);
    proj_gemm  <<<dim3(2, 32, 4), 256, 0, stream>>>(att, wproj, projbf, psum);
    bn_finalize<<<1,              256, 0, stream>>>(psum, stats);
    bn_apply   <<<4096,           256, 0, stream>>>(projbf, stats, gamma, beta, x, out);
}